// Round 1
// baseline (650.213 us; speedup 1.0000x reference)
//
#include <hip/hip_runtime.h>
#include <hip/hip_cooperative_groups.h>
#include <math.h>

namespace cg = cooperative_groups;

#define BATCH 128
#define NPRI  8732
#define CCH   512
#define HH    19
#define NHID  4096
#define FGC   19
#define GRID  512
#define KSPL  8

typedef unsigned short u16;
typedef __attribute__((ext_vector_type(8))) short bf16x8;
typedef __attribute__((ext_vector_type(4))) float f32x4;

// RNE fp32 -> bf16 (finite values)
__device__ __forceinline__ u16 f2bf(float f) {
  unsigned u = __float_as_uint(f);
  u += 0x7fff + ((u >> 16) & 1);
  return (u16)(u >> 16);
}

// Shared memory: one union reused across phases (max 15360 B -> 2 blocks/CU fine)
struct SMem {
  union {
    struct { float s[256]; int n[256]; } red;          // phase 1
    struct { u16 As[128 * 40]; u16 Bs[64 * 40]; } mm;  // phases 3,5
    float g3[4 * FGC];                                 // phase 7
  };
};

// ---------------------------------------------------------------------------
// Proven R2/R3 MFMA tile: 64-wide n-tile, BK=32, split-K over blockIdx>>6.
// A: [128][K] bf16, W: [K][4096] fp32 (converted to bf16 at staging).
// ---------------------------------------------------------------------------
__device__ void mfma_phase(const u16* __restrict__ A, const float* __restrict__ W,
                           float* __restrict__ part, int K, int Kper,
                           u16* As, u16* Bs) {
  const int N = NHID;
  int bid = blockIdx.x;
  int nb = bid & 63, ks = bid >> 6;
  int k0b = ks * Kper;
  int t = threadIdx.x;
  int lane = t & 63, wave = t >> 6;
  int q = lane >> 4, r = lane & 15;
  int wm = (wave & 1) * 64, wn = (wave >> 1) * 32;
  int n0 = nb * 64;

  f32x4 acc[4][2];
  #pragma unroll
  for (int i = 0; i < 4; i++)
    #pragma unroll
    for (int j = 0; j < 2; j++) {
      acc[i][j].x = 0.f; acc[i][j].y = 0.f; acc[i][j].z = 0.f; acc[i][j].w = 0.f;
    }

  int am = t >> 1, ah = (t & 1) * 16;  // A staging: row, 16-elem half
  int kp = t >> 4;                     // W staging: k-pair (0..15)
  int n4 = (t & 15) * 4;               // W staging: 4 contiguous n

  for (int k0 = k0b; k0 < k0b + Kper; k0 += 32) {
    const u16* asrc = A + (size_t)am * K + k0 + ah;
    uint4 a0 = *(const uint4*)asrc;
    uint4 a1 = *(const uint4*)(asrc + 8);
    const float* wsrc = W + (size_t)(k0 + 2 * kp) * N + n0 + n4;
    float4 w0 = *(const float4*)wsrc;        // k even
    float4 w1v = *(const float4*)(wsrc + N); // k odd
    __syncthreads();                 // previous iter's readers done
    *(uint4*)&As[am * 40 + ah]     = a0;
    *(uint4*)&As[am * 40 + ah + 8] = a1;
    {
      unsigned pk0 = (unsigned)f2bf(w0.x) | ((unsigned)f2bf(w1v.x) << 16);
      unsigned pk1 = (unsigned)f2bf(w0.y) | ((unsigned)f2bf(w1v.y) << 16);
      unsigned pk2 = (unsigned)f2bf(w0.z) | ((unsigned)f2bf(w1v.z) << 16);
      unsigned pk3 = (unsigned)f2bf(w0.w) | ((unsigned)f2bf(w1v.w) << 16);
      *(unsigned*)&Bs[(n4 + 0) * 40 + 2 * kp] = pk0;
      *(unsigned*)&Bs[(n4 + 1) * 40 + 2 * kp] = pk1;
      *(unsigned*)&Bs[(n4 + 2) * 40 + 2 * kp] = pk2;
      *(unsigned*)&Bs[(n4 + 3) * 40 + 2 * kp] = pk3;
    }
    __syncthreads();
    bf16x8 af[4], bfr[2];
    #pragma unroll
    for (int i = 0; i < 4; i++)
      af[i] = *(const bf16x8*)&As[(wm + 16 * i + r) * 40 + q * 8];
    #pragma unroll
    for (int j = 0; j < 2; j++)
      bfr[j] = *(const bf16x8*)&Bs[(wn + 16 * j + r) * 40 + q * 8];
    #pragma unroll
    for (int i = 0; i < 4; i++)
      #pragma unroll
      for (int j = 0; j < 2; j++)
        acc[i][j] = __builtin_amdgcn_mfma_f32_16x16x32_bf16(af[i], bfr[j],
                                                            acc[i][j], 0, 0, 0);
  }

  // epilogue: C row = wm+16i+q*4+reg, col = n0+wn+16j+r (verified)
  float* dst = part + (size_t)ks * (BATCH * NHID);
  #pragma unroll
  for (int i = 0; i < 4; i++)
    #pragma unroll
    for (int j = 0; j < 2; j++) {
      int col = n0 + wn + 16 * j + r;
      #pragma unroll
      for (int reg = 0; reg < 4; reg++) {
        int row = wm + 16 * i + q * 4 + reg;
        dst[(size_t)row * N + col] = acc[i][j][reg];
      }
    }
}

// ---------------------------------------------------------------------------
// One cooperative kernel: best-prior -> extract -> GEMM1 -> fin1 -> GEMM2
// -> fin2 -> GEMM3. 512 blocks x 256 threads, 6 grid syncs.
// ---------------------------------------------------------------------------
__global__ __launch_bounds__(256, 2) void fused_net(
    const float* __restrict__ loc, const float* __restrict__ conf,
    const float* __restrict__ priors, const float* __restrict__ features,
    const float* __restrict__ w1, const float* __restrict__ b1,
    const float* __restrict__ w2, const float* __restrict__ b2,
    const float* __restrict__ w3, const float* __restrict__ b3,
    float* __restrict__ out, float* __restrict__ part,
    u16* __restrict__ featb, u16* __restrict__ h1b, float* __restrict__ h2,
    int4* __restrict__ crop, int* __restrict__ vfl) {
  __shared__ __align__(16) SMem sm;
  cg::grid_group grid = cg::this_grid();
  int t = threadIdx.x;

  // ---- phase 1: best prior per batch (one block per batch) ----
  // argmax over sigmoid(c1-c0) where c1>c0  ==  argmax over d=c1-c0 where d>0
  // (exp/div are monotone, so selection + min-index tiebreak are identical).
  if (blockIdx.x < BATCH) {
    int b = blockIdx.x;
    const float4* cb = (const float4*)(conf + (size_t)b * NPRI * 2);
    float bd = -INFINITY; int bn = 0x7fffffff;
    for (int j = t; j < NPRI / 2; j += 256) {  // 4366 float4 = 2 priors each
      float4 v = cb[j];
      float d0 = v.y - v.x, d1 = v.w - v.z;
      if (d0 > bd) { bd = d0; bn = 2 * j; }      // strict > keeps first index
      if (d1 > bd) { bd = d1; bn = 2 * j + 1; }
    }
    sm.red.s[t] = bd; sm.red.n[t] = bn;
    __syncthreads();
    for (int off = 128; off > 0; off >>= 1) {
      if (t < off) {
        float s2 = sm.red.s[t + off]; int n2 = sm.red.n[t + off];
        if (s2 > sm.red.s[t] || (s2 == sm.red.s[t] && n2 < sm.red.n[t])) {
          sm.red.s[t] = s2; sm.red.n[t] = n2;
        }
      }
      __syncthreads();
    }
    if (t == 0) {
      float bdf = sm.red.s[0]; int bnf = sm.red.n[0];
      bool hc = bdf > 0.0f;                      // any car <=> best d > 0
      float r0 = 0.f, r1 = 0.f, r2 = 0.f, r3 = 0.f;
      bool valid = false;
      if (hc) {
        const float* lp = loc + ((size_t)b * NPRI + bnf) * 4;
        const float* pp = priors + (size_t)bnf * 4;
        float l0 = lp[0], l1 = lp[1], l2 = lp[2], l3 = lp[3];
        float pcx = pp[0], pcy = pp[1], pw = pp[2], ph = pp[3];
        float cx = pcx + (l0 * 0.1f) * pw;
        float cy = pcy + (l1 * 0.1f) * ph;
        float w = pw * expf(l2 * 0.2f);
        float h = ph * expf(l3 * 0.2f);
        float x1 = cx - 0.5f * w, y1 = cy - 0.5f * h;
        float x2 = x1 + w, y2 = y1 + h;
        valid = (x2 > x1) && (y2 > y1);
        r0 = fminf(fmaxf(x1, 0.f), 1.f);
        r1 = fminf(fmaxf(y1, 0.f), 1.f);
        r2 = fminf(fmaxf(x2, 0.f), 1.f);
        r3 = fminf(fmaxf(y2, 0.f), 1.f);
      }
      float* ob = out + BATCH * FGC;
      ob[b * 4 + 0] = r0; ob[b * 4 + 1] = r1;
      ob[b * 4 + 2] = r2; ob[b * 4 + 3] = r3;
      out[BATCH * FGC + BATCH * 4 + b] = valid ? 1.0f : 0.0f;
      const float stepF = (float)(300.0 / 19.0);
      float q0 = fminf(fmaxf(r0 * 300.0f, 0.0f), 300.0f) / stepF;
      float q1 = fminf(fmaxf(r1 * 300.0f, 0.0f), 300.0f) / stepF;
      float q2 = fminf(fmaxf(r2 * 300.0f, 0.0f), 300.0f) / stepF;
      float q3 = fminf(fmaxf(r3 * 300.0f, 0.0f), 300.0f) / stepF;
      int ix1 = (int)floorf(fminf(fmaxf(q0, 0.0f), 18.0f));
      int iy1 = (int)floorf(fminf(fmaxf(q1, 0.0f), 18.0f));
      int ix2 = (int)floorf(fminf(fmaxf(q2, 0.0f), 18.0f));
      int iy2 = (int)floorf(fminf(fmaxf(q3, 0.0f), 18.0f));
      crop[b] = make_int4(ix1, iy1, ix2, iy2);
      vfl[b] = valid ? 1 : 0;
    }
  }
  grid.sync();

  // ---- phase 2: crop + global max pool -> bf16 feat ----
  {
    int wave = t >> 6, lane = t & 63;
    for (int v = blockIdx.x; v < BATCH * (CCH / 4); v += GRID) {
      int b = v >> 7, tile = v & 127;
      int c = tile * 4 + wave;
      if (!vfl[b]) { if (lane == 0) featb[b * CCH + c] = 0; continue; }
      int4 cr = crop[b];
      int wcnt = cr.z - cr.x + 1;
      int cnt = wcnt * (cr.w - cr.y + 1);
      const float* p = features + (size_t)(b * CCH + c) * (HH * HH);
      float m = -INFINITY;
      for (int i = lane; i < cnt; i += 64) {
        int yy = cr.y + i / wcnt;
        int xx = cr.x + i % wcnt;
        m = fmaxf(m, p[yy * HH + xx]);
      }
      #pragma unroll
      for (int off = 32; off > 0; off >>= 1) m = fmaxf(m, __shfl_xor(m, off));
      if (lane == 0) featb[b * CCH + c] = f2bf(m);
    }
  }
  grid.sync();

  // ---- phase 3: GEMM1 (128x512 @ 512x4096), split-K=8, all 512 blocks ----
  mfma_phase(featb, w1, part, CCH, CCH / KSPL, sm.mm.As, sm.mm.Bs);
  grid.sync();

  // ---- phase 4: sum 8 partials + b1 + relu -> bf16 h1 (1 float4/thread) ----
  {
    int idx = (blockIdx.x * 256 + t) * 4;
    float4 s = *(const float4*)(part + idx);
    #pragma unroll
    for (int p = 1; p < KSPL; p++) {
      float4 v = *(const float4*)(part + (size_t)p * (BATCH * NHID) + idx);
      s.x += v.x; s.y += v.y; s.z += v.z; s.w += v.w;
    }
    float4 bv = *(const float4*)(b1 + (idx & (NHID - 1)));
    s.x = fmaxf(s.x + bv.x, 0.0f); s.y = fmaxf(s.y + bv.y, 0.0f);
    s.z = fmaxf(s.z + bv.z, 0.0f); s.w = fmaxf(s.w + bv.w, 0.0f);
    ushort4 o;
    o.x = f2bf(s.x); o.y = f2bf(s.y); o.z = f2bf(s.z); o.w = f2bf(s.w);
    *(ushort4*)(h1b + idx) = o;
  }
  grid.sync();

  // ---- phase 5: GEMM2 (128x4096 @ 4096x4096), split-K=8 ----
  mfma_phase(h1b, w2, part, NHID, NHID / KSPL, sm.mm.As, sm.mm.Bs);
  grid.sync();

  // ---- phase 6: sum 8 partials + b2 + relu -> fp32 h2 ----
  {
    int idx = (blockIdx.x * 256 + t) * 4;
    float4 s = *(const float4*)(part + idx);
    #pragma unroll
    for (int p = 1; p < KSPL; p++) {
      float4 v = *(const float4*)(part + (size_t)p * (BATCH * NHID) + idx);
      s.x += v.x; s.y += v.y; s.z += v.z; s.w += v.w;
    }
    float4 bv = *(const float4*)(b2 + (idx & (NHID - 1)));
    s.x = fmaxf(s.x + bv.x, 0.0f); s.y = fmaxf(s.y + bv.y, 0.0f);
    s.z = fmaxf(s.z + bv.z, 0.0f); s.w = fmaxf(s.w + bv.w, 0.0f);
    *(float4*)(h2 + idx) = s;
  }
  grid.sync();

  // ---- phase 7: final projection (one block per batch row) ----
  if (blockIdx.x < BATCH) {
    int b = blockIdx.x;
    float acc[FGC];
    #pragma unroll
    for (int j = 0; j < FGC; j++) acc[j] = 0.0f;
    const float* hp = h2 + (size_t)b * NHID;
    for (int k = t; k < NHID; k += 256) {
      float hv = hp[k];
      const float* wp = w3 + (size_t)k * FGC;
      #pragma unroll
      for (int j = 0; j < FGC; j++) acc[j] += hv * wp[j];
    }
    int lane = t & 63, wave = t >> 6;
    #pragma unroll
    for (int j = 0; j < FGC; j++) {
      #pragma unroll
      for (int off = 32; off > 0; off >>= 1)
        acc[j] += __shfl_xor(acc[j], off);
    }
    if (lane == 0) {
      #pragma unroll
      for (int j = 0; j < FGC; j++) sm.g3[wave * FGC + j] = acc[j];
    }
    __syncthreads();
    if (t < FGC) {
      float s = sm.g3[t] + sm.g3[FGC + t] + sm.g3[2 * FGC + t] + sm.g3[3 * FGC + t];
      out[b * FGC + t] = s + b3[t];
    }
  }
}

// ---------------------------------------------------------------------------
extern "C" void kernel_launch(void* const* d_in, const int* in_sizes, int n_in,
                              void* d_out, int out_size, void* d_ws, size_t ws_size,
                              hipStream_t stream) {
  const float* loc      = (const float*)d_in[0];
  const float* conf     = (const float*)d_in[1];
  const float* priors   = (const float*)d_in[2];
  const float* features = (const float*)d_in[3];
  const float* w1 = (const float*)d_in[4];
  const float* b1 = (const float*)d_in[5];
  const float* w2 = (const float*)d_in[6];
  const float* b2 = (const float*)d_in[7];
  const float* w3 = (const float*)d_in[8];
  const float* b3 = (const float*)d_in[9];
  float* out = (float*)d_out;      // [128*19 fg][128*4 boxes][128 valid]

  char* ws = (char*)d_ws;
  float* part  = (float*)ws;                                   // 16 MB (8 slabs)
  u16*   featb = (u16*)(ws + (size_t)16 * 1024 * 1024);        // 128 KB
  u16*   h1b   = (u16*)(ws + (size_t)16 * 1024 * 1024 + 256 * 1024);  // 1 MB
  float* h2    = (float*)(ws + (size_t)18 * 1024 * 1024);      // 2 MB
  int4*  crop  = (int4*)(ws + (size_t)20 * 1024 * 1024);       // 2 KB
  int*   vfl   = (int*)(crop + BATCH);

  void* args[] = {
    (void*)&loc, (void*)&conf, (void*)&priors, (void*)&features,
    (void*)&w1, (void*)&b1, (void*)&w2, (void*)&b2, (void*)&w3, (void*)&b3,
    (void*)&out, (void*)&part, (void*)&featb, (void*)&h1b, (void*)&h2,
    (void*)&crop, (void*)&vfl
  };
  hipLaunchCooperativeKernel((void*)fused_net, dim3(GRID), dim3(256),
                             args, 0, stream);
}

// Round 2
// 275.109 us; speedup vs baseline: 2.3635x; 2.3635x over previous
//
#include <hip/hip_runtime.h>
#include <math.h>

#define BATCH 128
#define NPRI  8732
#define CCH   512
#define HH    19
#define NHID  4096
#define FGC   19

typedef unsigned short u16;
typedef __attribute__((ext_vector_type(8))) short bf16x8;
typedef __attribute__((ext_vector_type(4))) float f32x4;

// RNE fp32 -> bf16 (finite values)
__device__ __forceinline__ u16 f2bf(float f) {
  unsigned u = __float_as_uint(f);
  u += 0x7fff + ((u >> 16) & 1);
  return (u16)(u >> 16);
}

// ---------------------------------------------------------------------------
// K1: best prior per batch, one block per batch (merged partial+final).
// argmax over p1 where argmax-class==car  ==  argmax over d=c1-c0 where d>0
// (sigmoid is strictly monotone; sign test identical). Verified passing in R1.
// ---------------------------------------------------------------------------
__global__ void k_best(const float* __restrict__ conf,
                       const float* __restrict__ loc,
                       const float* __restrict__ priors,
                       float* __restrict__ out_boxes,
                       float* __restrict__ out_valid,
                       int4* __restrict__ crop, int* __restrict__ vflag) {
  int b = blockIdx.x;
  int t = threadIdx.x;
  const float4* cb = (const float4*)(conf + (size_t)b * NPRI * 2);
  float bd = -INFINITY; int bn = 0x7fffffff;
  for (int j = t; j < NPRI / 2; j += 256) {   // 4366 float4 = 2 priors each
    float4 v = cb[j];
    float d0 = v.y - v.x, d1 = v.w - v.z;
    if (d0 > bd) { bd = d0; bn = 2 * j; }     // strict > keeps first index
    if (d1 > bd) { bd = d1; bn = 2 * j + 1; }
  }
  __shared__ float ls[256]; __shared__ int li[256];
  ls[t] = bd; li[t] = bn;
  __syncthreads();
  for (int off = 128; off > 0; off >>= 1) {
    if (t < off) {
      float s2 = ls[t + off]; int n2 = li[t + off];
      if (s2 > ls[t] || (s2 == ls[t] && n2 < li[t])) { ls[t] = s2; li[t] = n2; }
    }
    __syncthreads();
  }
  if (t == 0) {
    float bdf = ls[0]; int bnf = li[0];
    bool hc = bdf > 0.0f;                     // any car <=> best d > 0
    float r0 = 0.f, r1 = 0.f, r2 = 0.f, r3 = 0.f;
    bool valid = false;
    if (hc) {
      const float* lp = loc + ((size_t)b * NPRI + bnf) * 4;
      const float* pp = priors + (size_t)bnf * 4;
      float l0 = lp[0], l1 = lp[1], l2 = lp[2], l3 = lp[3];
      float pcx = pp[0], pcy = pp[1], pw = pp[2], ph = pp[3];
      float cx = pcx + (l0 * 0.1f) * pw;
      float cy = pcy + (l1 * 0.1f) * ph;
      float w = pw * expf(l2 * 0.2f);
      float h = ph * expf(l3 * 0.2f);
      float x1 = cx - 0.5f * w, y1 = cy - 0.5f * h;
      float x2 = x1 + w, y2 = y1 + h;
      valid = (x2 > x1) && (y2 > y1);
      r0 = fminf(fmaxf(x1, 0.f), 1.f);
      r1 = fminf(fmaxf(y1, 0.f), 1.f);
      r2 = fminf(fmaxf(x2, 0.f), 1.f);
      r3 = fminf(fmaxf(y2, 0.f), 1.f);
    }
    out_boxes[b * 4 + 0] = r0; out_boxes[b * 4 + 1] = r1;
    out_boxes[b * 4 + 2] = r2; out_boxes[b * 4 + 3] = r3;
    out_valid[b] = valid ? 1.0f : 0.0f;
    const float stepF = (float)(300.0 / 19.0);
    float q0 = fminf(fmaxf(r0 * 300.0f, 0.0f), 300.0f) / stepF;
    float q1 = fminf(fmaxf(r1 * 300.0f, 0.0f), 300.0f) / stepF;
    float q2 = fminf(fmaxf(r2 * 300.0f, 0.0f), 300.0f) / stepF;
    float q3 = fminf(fmaxf(r3 * 300.0f, 0.0f), 300.0f) / stepF;
    int ix1 = (int)floorf(fminf(fmaxf(q0, 0.0f), 18.0f));
    int iy1 = (int)floorf(fminf(fmaxf(q1, 0.0f), 18.0f));
    int ix2 = (int)floorf(fminf(fmaxf(q2, 0.0f), 18.0f));
    int iy2 = (int)floorf(fminf(fmaxf(q3, 0.0f), 18.0f));
    crop[b] = make_int4(ix1, iy1, ix2, iy2);
    vflag[b] = valid ? 1 : 0;
  }
}

// ---------------------------------------------------------------------------
// K2: crop + global max pool -> bf16 feat.
// Coalesced full-plane read (361 floats, lane-consecutive) + in-crop mask,
// instead of div/mod-scattered row-segment reads.
// ---------------------------------------------------------------------------
__global__ void k_extract(const float* __restrict__ fin,
                          const int4* __restrict__ crop,
                          const int* __restrict__ vflag,
                          u16* __restrict__ feat) {
  int blk = blockIdx.x;
  int b = blk >> 7;
  int tile = blk & 127;
  int wave = threadIdx.x >> 6;
  int lane = threadIdx.x & 63;
  int c = tile * 4 + wave;
  if (!vflag[b]) {
    if (lane == 0) feat[b * CCH + c] = 0;
    return;
  }
  int4 cr = crop[b];
  const float* p = fin + (size_t)(b * CCH + c) * (HH * HH);
  float m = -INFINITY;
  #pragma unroll
  for (int it = 0; it < 6; it++) {            // 6*64 = 384 >= 361
    int idx = it * 64 + lane;
    if (idx < HH * HH) {
      int yy = idx / HH, xx = idx - yy * HH;  // const divisor -> magic mul
      bool in = (yy >= cr.y) & (yy <= cr.w) & (xx >= cr.x) & (xx <= cr.z);
      float v = p[idx];
      if (in) m = fmaxf(m, v);
    }
  }
  #pragma unroll
  for (int off = 32; off > 0; off >>= 1) m = fmaxf(m, __shfl_xor(m, off));
  if (lane == 0) feat[b * CCH + c] = f2bf(m);
}

// ---------------------------------------------------------------------------
// K3: GEMM1 (128x512 @ 512x4096) full-K, fused bias+relu+bf16 epilogue.
// 64 blocks (one per 64-col n-tile), proven R2 tile structure.
// ---------------------------------------------------------------------------
__global__ __launch_bounds__(256) void k_gemm1(const u16* __restrict__ A,
                                               const float* __restrict__ W,
                                               const float* __restrict__ bias,
                                               u16* __restrict__ H1) {
  const int N = NHID, K = CCH;
  int nb = blockIdx.x;
  int t = threadIdx.x;
  int lane = t & 63, wave = t >> 6;
  int q = lane >> 4, r = lane & 15;
  int wm = (wave & 1) * 64, wn = (wave >> 1) * 32;
  int n0 = nb * 64;

  __shared__ u16 As[128 * 40];
  __shared__ u16 Bs[64 * 40];

  f32x4 acc[4][2];
  #pragma unroll
  for (int i = 0; i < 4; i++)
    #pragma unroll
    for (int j = 0; j < 2; j++) {
      acc[i][j].x = 0.f; acc[i][j].y = 0.f; acc[i][j].z = 0.f; acc[i][j].w = 0.f;
    }

  int am = t >> 1, ah = (t & 1) * 16;
  int kp = t >> 4;
  int n4 = (t & 15) * 4;

  for (int k0 = 0; k0 < K; k0 += 32) {
    const u16* asrc = A + (size_t)am * K + k0 + ah;
    uint4 a0 = *(const uint4*)asrc;
    uint4 a1 = *(const uint4*)(asrc + 8);
    const float* wsrc = W + (size_t)(k0 + 2 * kp) * N + n0 + n4;
    float4 w0 = *(const float4*)wsrc;
    float4 w1v = *(const float4*)(wsrc + N);
    __syncthreads();
    *(uint4*)&As[am * 40 + ah]     = a0;
    *(uint4*)&As[am * 40 + ah + 8] = a1;
    {
      unsigned pk0 = (unsigned)f2bf(w0.x) | ((unsigned)f2bf(w1v.x) << 16);
      unsigned pk1 = (unsigned)f2bf(w0.y) | ((unsigned)f2bf(w1v.y) << 16);
      unsigned pk2 = (unsigned)f2bf(w0.z) | ((unsigned)f2bf(w1v.z) << 16);
      unsigned pk3 = (unsigned)f2bf(w0.w) | ((unsigned)f2bf(w1v.w) << 16);
      *(unsigned*)&Bs[(n4 + 0) * 40 + 2 * kp] = pk0;
      *(unsigned*)&Bs[(n4 + 1) * 40 + 2 * kp] = pk1;
      *(unsigned*)&Bs[(n4 + 2) * 40 + 2 * kp] = pk2;
      *(unsigned*)&Bs[(n4 + 3) * 40 + 2 * kp] = pk3;
    }
    __syncthreads();
    bf16x8 af[4], bfr[2];
    #pragma unroll
    for (int i = 0; i < 4; i++)
      af[i] = *(const bf16x8*)&As[(wm + 16 * i + r) * 40 + q * 8];
    #pragma unroll
    for (int j = 0; j < 2; j++)
      bfr[j] = *(const bf16x8*)&Bs[(wn + 16 * j + r) * 40 + q * 8];
    #pragma unroll
    for (int i = 0; i < 4; i++)
      #pragma unroll
      for (int j = 0; j < 2; j++)
        acc[i][j] = __builtin_amdgcn_mfma_f32_16x16x32_bf16(af[i], bfr[j],
                                                            acc[i][j], 0, 0, 0);
  }

  // fused epilogue: bias + relu + bf16, direct to H1 (row=batch, col=hidden)
  #pragma unroll
  for (int j = 0; j < 2; j++) {
    int col = n0 + wn + 16 * j + r;
    float bv = bias[col];
    #pragma unroll
    for (int i = 0; i < 4; i++) {
      #pragma unroll
      for (int reg = 0; reg < 4; reg++) {
        int row = wm + 16 * i + q * 4 + reg;
        float v = fmaxf(acc[i][j][reg] + bv, 0.0f);
        H1[(size_t)row * N + col] = f2bf(v);
      }
    }
  }
}

// ---------------------------------------------------------------------------
// K4: GEMM2 split-K MFMA (proven R2/R3 structure, KSPL=8)
// ---------------------------------------------------------------------------
template <int KSPL>
__global__ __launch_bounds__(256) void k_mfma(const u16* __restrict__ A,
                                              const float* __restrict__ W,
                                              float* __restrict__ part, int K) {
  const int N = NHID;
  int nb = blockIdx.x;
  int ks = blockIdx.y;
  int Kper = K / KSPL;
  int k0b = ks * Kper;
  int t = threadIdx.x;
  int lane = t & 63, wave = t >> 6;
  int q = lane >> 4, r = lane & 15;

  __shared__ u16 As[128 * 40];
  __shared__ u16 Bs[64 * 40];

  int wm = (wave & 1) * 64;
  int wn = (wave >> 1) * 32;
  int n0 = nb * 64;

  f32x4 acc[4][2];
  #pragma unroll
  for (int i = 0; i < 4; i++)
    #pragma unroll
    for (int j = 0; j < 2; j++) {
      acc[i][j].x = 0.f; acc[i][j].y = 0.f; acc[i][j].z = 0.f; acc[i][j].w = 0.f;
    }

  int am = t >> 1, ah = (t & 1) * 16;
  int kp = t >> 4;
  int n4 = (t & 15) * 4;

  for (int k0 = k0b; k0 < k0b + Kper; k0 += 32) {
    const u16* asrc = A + (size_t)am * K + k0 + ah;
    uint4 a0 = *(const uint4*)asrc;
    uint4 a1 = *(const uint4*)(asrc + 8);
    const float* wsrc = W + (size_t)(k0 + 2 * kp) * N + n0 + n4;
    float4 w0 = *(const float4*)wsrc;
    float4 w1v = *(const float4*)(wsrc + N);
    __syncthreads();
    *(uint4*)&As[am * 40 + ah]     = a0;
    *(uint4*)&As[am * 40 + ah + 8] = a1;
    {
      unsigned pk0 = (unsigned)f2bf(w0.x) | ((unsigned)f2bf(w1v.x) << 16);
      unsigned pk1 = (unsigned)f2bf(w0.y) | ((unsigned)f2bf(w1v.y) << 16);
      unsigned pk2 = (unsigned)f2bf(w0.z) | ((unsigned)f2bf(w1v.z) << 16);
      unsigned pk3 = (unsigned)f2bf(w0.w) | ((unsigned)f2bf(w1v.w) << 16);
      *(unsigned*)&Bs[(n4 + 0) * 40 + 2 * kp] = pk0;
      *(unsigned*)&Bs[(n4 + 1) * 40 + 2 * kp] = pk1;
      *(unsigned*)&Bs[(n4 + 2) * 40 + 2 * kp] = pk2;
      *(unsigned*)&Bs[(n4 + 3) * 40 + 2 * kp] = pk3;
    }
    __syncthreads();
    bf16x8 af[4], bfr[2];
    #pragma unroll
    for (int i = 0; i < 4; i++)
      af[i] = *(const bf16x8*)&As[(wm + 16 * i + r) * 40 + q * 8];
    #pragma unroll
    for (int j = 0; j < 2; j++)
      bfr[j] = *(const bf16x8*)&Bs[(wn + 16 * j + r) * 40 + q * 8];
    #pragma unroll
    for (int i = 0; i < 4; i++)
      #pragma unroll
      for (int j = 0; j < 2; j++)
        acc[i][j] = __builtin_amdgcn_mfma_f32_16x16x32_bf16(af[i], bfr[j],
                                                            acc[i][j], 0, 0, 0);
  }

  float* dst = part + (size_t)ks * (BATCH * NHID);
  #pragma unroll
  for (int i = 0; i < 4; i++)
    #pragma unroll
    for (int j = 0; j < 2; j++) {
      int col = n0 + wn + 16 * j + r;
      #pragma unroll
      for (int reg = 0; reg < 4; reg++) {
        int row = wm + 16 * i + q * 4 + reg;
        dst[(size_t)row * N + col] = acc[i][j][reg];
      }
    }
}

// ---------------------------------------------------------------------------
// K5: sum KSPL partials + bias + relu -> fp32 h2
// ---------------------------------------------------------------------------
template <int KSPL>
__global__ void k_finalize(const float* __restrict__ part,
                           const float* __restrict__ bias,
                           float* __restrict__ outf) {
  int idx = (blockIdx.x * 256 + threadIdx.x) * 4;
  float4 s = *(const float4*)(part + idx);
  #pragma unroll
  for (int p = 1; p < KSPL; p++) {
    float4 v = *(const float4*)(part + (size_t)p * (BATCH * NHID) + idx);
    s.x += v.x; s.y += v.y; s.z += v.z; s.w += v.w;
  }
  float4 bv = *(const float4*)(bias + (idx & (NHID - 1)));
  s.x = fmaxf(s.x + bv.x, 0.0f); s.y = fmaxf(s.y + bv.y, 0.0f);
  s.z = fmaxf(s.z + bv.z, 0.0f); s.w = fmaxf(s.w + bv.w, 0.0f);
  *(float4*)(outf + idx) = s;
}

// ---------------------------------------------------------------------------
// K6/K7: final projection partials + reduce (proven R2 versions)
// ---------------------------------------------------------------------------
__global__ void k_gemm3p(const float* __restrict__ h2,
                         const float* __restrict__ w3,
                         float* __restrict__ part3) {
  int kc = blockIdx.x;             // 128 chunks of 32 k
  int t = threadIdx.x;             // 128 threads, m = t
  __shared__ float wl[32 * FGC];
  for (int i = t; i < 32 * FGC; i += 128) wl[i] = w3[kc * 32 * FGC + i];
  __syncthreads();
  const float* hp = h2 + (size_t)t * NHID + kc * 32;
  float acc[FGC];
  #pragma unroll
  for (int j = 0; j < FGC; j++) acc[j] = 0.0f;
  for (int k = 0; k < 32; k++) {
    float hv = hp[k];
    const float* wp = &wl[k * FGC];
    #pragma unroll
    for (int j = 0; j < FGC; j++) acc[j] += hv * wp[j];
  }
  float* dst = part3 + (size_t)kc * (BATCH * FGC) + t * FGC;
  #pragma unroll
  for (int j = 0; j < FGC; j++) dst[j] = acc[j];
}

__global__ void k_fin3(const float* __restrict__ part3,
                       const float* __restrict__ b3,
                       float* __restrict__ out) {
  int j = blockIdx.x * 256 + threadIdx.x;
  if (j >= BATCH * FGC) return;
  float s = 0.0f;
  for (int p = 0; p < 128; p++) s += part3[(size_t)p * (BATCH * FGC) + j];
  out[j] = s + b3[j % FGC];
}

// ---------------------------------------------------------------------------
extern "C" void kernel_launch(void* const* d_in, const int* in_sizes, int n_in,
                              void* d_out, int out_size, void* d_ws, size_t ws_size,
                              hipStream_t stream) {
  const float* loc      = (const float*)d_in[0];
  const float* conf     = (const float*)d_in[1];
  const float* priors   = (const float*)d_in[2];
  const float* features = (const float*)d_in[3];
  const float* w1 = (const float*)d_in[4];
  const float* b1 = (const float*)d_in[5];
  const float* w2 = (const float*)d_in[6];
  const float* b2 = (const float*)d_in[7];
  const float* w3 = (const float*)d_in[8];
  const float* b3 = (const float*)d_in[9];
  float* out = (float*)d_out;      // [128*19 fg][128*4 boxes][128 valid]

  char* ws = (char*)d_ws;
  float* part  = (float*)ws;                                          // 16 MB
  float* part3 = (float*)(ws + (size_t)16 * 1024 * 1024);             // 1.25 MB
  float* h2    = (float*)(ws + (size_t)18 * 1024 * 1024);             // 2 MB
  u16*   featb = (u16*)(ws + (size_t)20 * 1024 * 1024);               // 128 KB
  u16*   h1b   = (u16*)(ws + (size_t)20 * 1024 * 1024 + 256 * 1024);  // 1 MB
  int4*  crop  = (int4*)(ws + (size_t)21 * 1024 * 1024 + 512 * 1024); // 2 KB
  int*   vfl   = (int*)(crop + BATCH);

  k_best<<<BATCH, 256, 0, stream>>>(conf, loc, priors,
                                    out + BATCH * FGC,
                                    out + BATCH * FGC + BATCH * 4, crop, vfl);
  k_extract<<<BATCH * (CCH / 4), 256, 0, stream>>>(features, crop, vfl, featb);
  k_gemm1<<<64, 256, 0, stream>>>(featb, w1, b1, h1b);
  k_mfma<8><<<dim3(64, 8), 256, 0, stream>>>(h1b, w2, part, NHID);
  k_finalize<8><<<512, 256, 0, stream>>>(part, b2, h2);
  k_gemm3p<<<128, 128, 0, stream>>>(h2, w3, part3);
  k_fin3<<<10, 256, 0, stream>>>(part3, b3, out);
}

// Round 3
// 260.650 us; speedup vs baseline: 2.4946x; 1.0555x over previous
//
#include <hip/hip_runtime.h>
#include <hip/hip_bf16.h>
#include <math.h>

#define BATCH 128
#define NPRI  8732
#define CCH   512
#define HH    19
#define NHID  4096
#define FGC   19

typedef unsigned short u16;
typedef __attribute__((ext_vector_type(8))) short bf16x8;
typedef __attribute__((ext_vector_type(4))) float f32x4;

// RNE fp32 -> bf16 (finite values)
__device__ __forceinline__ u16 f2bf(float f) {
  unsigned u = __float_as_uint(f);
  u += 0x7fff + ((u >> 16) & 1);
  return (u16)(u >> 16);
}

// ---------------------------------------------------------------------------
// K1: best prior per batch, one block per batch (merged partial+final).
// argmax over p1 where argmax-class==car  ==  argmax over d=c1-c0 where d>0
// (softmax is strictly monotone in the logit difference). Proven R1/R2.
// ---------------------------------------------------------------------------
__global__ void k_best(const float* __restrict__ conf,
                       const float* __restrict__ loc,
                       const float* __restrict__ priors,
                       float* __restrict__ out_boxes,
                       float* __restrict__ out_valid,
                       int4* __restrict__ crop, int* __restrict__ vflag) {
  int b = blockIdx.x;
  int t = threadIdx.x;
  const float4* cb = (const float4*)(conf + (size_t)b * NPRI * 2);
  float bd = -INFINITY; int bn = 0x7fffffff;
  for (int j = t; j < NPRI / 2; j += 256) {   // 4366 float4 = 2 priors each
    float4 v = cb[j];
    float d0 = v.y - v.x, d1 = v.w - v.z;
    if (d0 > bd) { bd = d0; bn = 2 * j; }     // strict > keeps first index
    if (d1 > bd) { bd = d1; bn = 2 * j + 1; }
  }
  __shared__ float ls[256]; __shared__ int li[256];
  ls[t] = bd; li[t] = bn;
  __syncthreads();
  for (int off = 128; off > 0; off >>= 1) {
    if (t < off) {
      float s2 = ls[t + off]; int n2 = li[t + off];
      if (s2 > ls[t] || (s2 == ls[t] && n2 < li[t])) { ls[t] = s2; li[t] = n2; }
    }
    __syncthreads();
  }
  if (t == 0) {
    float bdf = ls[0]; int bnf = li[0];
    bool hc = bdf > 0.0f;                     // any car <=> best d > 0
    float r0 = 0.f, r1 = 0.f, r2 = 0.f, r3 = 0.f;
    bool valid = false;
    if (hc) {
      const float* lp = loc + ((size_t)b * NPRI + bnf) * 4;
      const float* pp = priors + (size_t)bnf * 4;
      float l0 = lp[0], l1 = lp[1], l2 = lp[2], l3 = lp[3];
      float pcx = pp[0], pcy = pp[1], pw = pp[2], ph = pp[3];
      float cx = pcx + (l0 * 0.1f) * pw;
      float cy = pcy + (l1 * 0.1f) * ph;
      float w = pw * expf(l2 * 0.2f);
      float h = ph * expf(l3 * 0.2f);
      float x1 = cx - 0.5f * w, y1 = cy - 0.5f * h;
      float x2 = x1 + w, y2 = y1 + h;
      valid = (x2 > x1) && (y2 > y1);
      r0 = fminf(fmaxf(x1, 0.f), 1.f);
      r1 = fminf(fmaxf(y1, 0.f), 1.f);
      r2 = fminf(fmaxf(x2, 0.f), 1.f);
      r3 = fminf(fmaxf(y2, 0.f), 1.f);
    }
    out_boxes[b * 4 + 0] = r0; out_boxes[b * 4 + 1] = r1;
    out_boxes[b * 4 + 2] = r2; out_boxes[b * 4 + 3] = r3;
    out_valid[b] = valid ? 1.0f : 0.0f;
    const float stepF = (float)(300.0 / 19.0);
    float q0 = fminf(fmaxf(r0 * 300.0f, 0.0f), 300.0f) / stepF;
    float q1 = fminf(fmaxf(r1 * 300.0f, 0.0f), 300.0f) / stepF;
    float q2 = fminf(fmaxf(r2 * 300.0f, 0.0f), 300.0f) / stepF;
    float q3 = fminf(fmaxf(r3 * 300.0f, 0.0f), 300.0f) / stepF;
    int ix1 = (int)floorf(fminf(fmaxf(q0, 0.0f), 18.0f));
    int iy1 = (int)floorf(fminf(fmaxf(q1, 0.0f), 18.0f));
    int ix2 = (int)floorf(fminf(fmaxf(q2, 0.0f), 18.0f));
    int iy2 = (int)floorf(fminf(fmaxf(q3, 0.0f), 18.0f));
    crop[b] = make_int4(ix1, iy1, ix2, iy2);
    vflag[b] = valid ? 1 : 0;
  }
}

// ---------------------------------------------------------------------------
// K2: crop + global max pool -> bf16 feat  (R0-proven crop-only reads;
// full-plane variant regressed ~15 us in R2)
// ---------------------------------------------------------------------------
__global__ void k_extract(const float* __restrict__ fin,
                          const int4* __restrict__ crop,
                          const int* __restrict__ vflag,
                          u16* __restrict__ feat) {
  int blk = blockIdx.x;
  int b = blk >> 7;
  int tile = blk & 127;
  int wave = threadIdx.x >> 6;
  int lane = threadIdx.x & 63;
  int c = tile * 4 + wave;
  if (!vflag[b]) {
    if (lane == 0) feat[b * CCH + c] = 0;
    return;
  }
  int4 cr = crop[b];
  int wcnt = cr.z - cr.x + 1;
  int cnt = wcnt * (cr.w - cr.y + 1);
  const float* p = fin + (size_t)(b * CCH + c) * (HH * HH);
  float m = -INFINITY;
  for (int i = lane; i < cnt; i += 64) {
    int yy = cr.y + i / wcnt;
    int xx = cr.x + i % wcnt;
    m = fmaxf(m, p[yy * HH + xx]);
  }
  #pragma unroll
  for (int off = 32; off > 0; off >>= 1) m = fmaxf(m, __shfl_xor(m, off));
  if (lane == 0) feat[b * CCH + c] = f2bf(m);
}

// ---------------------------------------------------------------------------
// K3: split-K MFMA GEMM (R0-proven structure). W staged fp32->bf16 via
// packed cvt (v_cvt_pk_bf16_f32), same RNE numerics as f2bf.
// ---------------------------------------------------------------------------
template <int KSPL>
__global__ __launch_bounds__(256) void k_mfma(const u16* __restrict__ A,
                                              const float* __restrict__ W,
                                              float* __restrict__ part, int K) {
  const int N = NHID;
  int nb = blockIdx.x;
  int ks = blockIdx.y;
  int Kper = K / KSPL;
  int k0b = ks * Kper;
  int t = threadIdx.x;
  int lane = t & 63, wave = t >> 6;
  int q = lane >> 4, r = lane & 15;

  __shared__ u16 As[128 * 40];
  __shared__ u16 Bs[64 * 40];

  int wm = (wave & 1) * 64;
  int wn = (wave >> 1) * 32;
  int n0 = nb * 64;

  f32x4 acc[4][2];
  #pragma unroll
  for (int i = 0; i < 4; i++)
    #pragma unroll
    for (int j = 0; j < 2; j++) {
      acc[i][j].x = 0.f; acc[i][j].y = 0.f; acc[i][j].z = 0.f; acc[i][j].w = 0.f;
    }

  int am = t >> 1, ah = (t & 1) * 16;
  int kp = t >> 4;
  int n4 = (t & 15) * 4;

  for (int k0 = k0b; k0 < k0b + Kper; k0 += 32) {
    const u16* asrc = A + (size_t)am * K + k0 + ah;
    uint4 a0 = *(const uint4*)asrc;
    uint4 a1 = *(const uint4*)(asrc + 8);
    const float* wsrc = W + (size_t)(k0 + 2 * kp) * N + n0 + n4;
    float4 w0 = *(const float4*)wsrc;        // k even
    float4 w1v = *(const float4*)(wsrc + N); // k odd
    __syncthreads();
    *(uint4*)&As[am * 40 + ah]     = a0;
    *(uint4*)&As[am * 40 + ah + 8] = a1;
    {
      __hip_bfloat162 p0 = __float22bfloat162_rn(make_float2(w0.x, w1v.x));
      __hip_bfloat162 p1 = __float22bfloat162_rn(make_float2(w0.y, w1v.y));
      __hip_bfloat162 p2 = __float22bfloat162_rn(make_float2(w0.z, w1v.z));
      __hip_bfloat162 p3 = __float22bfloat162_rn(make_float2(w0.w, w1v.w));
      *(__hip_bfloat162*)&Bs[(n4 + 0) * 40 + 2 * kp] = p0;
      *(__hip_bfloat162*)&Bs[(n4 + 1) * 40 + 2 * kp] = p1;
      *(__hip_bfloat162*)&Bs[(n4 + 2) * 40 + 2 * kp] = p2;
      *(__hip_bfloat162*)&Bs[(n4 + 3) * 40 + 2 * kp] = p3;
    }
    __syncthreads();
    bf16x8 af[4], bfr[2];
    #pragma unroll
    for (int i = 0; i < 4; i++)
      af[i] = *(const bf16x8*)&As[(wm + 16 * i + r) * 40 + q * 8];
    #pragma unroll
    for (int j = 0; j < 2; j++)
      bfr[j] = *(const bf16x8*)&Bs[(wn + 16 * j + r) * 40 + q * 8];
    #pragma unroll
    for (int i = 0; i < 4; i++)
      #pragma unroll
      for (int j = 0; j < 2; j++)
        acc[i][j] = __builtin_amdgcn_mfma_f32_16x16x32_bf16(af[i], bfr[j],
                                                            acc[i][j], 0, 0, 0);
  }

  // epilogue: C row = wm+16i+q*4+reg, col = n0+wn+16j+r (verified)
  float* dst = part + (size_t)ks * (BATCH * NHID);
  #pragma unroll
  for (int i = 0; i < 4; i++)
    #pragma unroll
    for (int j = 0; j < 2; j++) {
      int col = n0 + wn + 16 * j + r;
      #pragma unroll
      for (int reg = 0; reg < 4; reg++) {
        int row = wm + 16 * i + q * 4 + reg;
        dst[(size_t)row * N + col] = acc[i][j][reg];
      }
    }
}

// ---------------------------------------------------------------------------
// K4: sum KSPL partials + bias + relu -> bf16 (h1 path)
// ---------------------------------------------------------------------------
template <int KSPL>
__global__ void k_finalize_bf16(const float* __restrict__ part,
                                const float* __restrict__ bias,
                                u16* __restrict__ outb) {
  int idx = (blockIdx.x * 256 + threadIdx.x) * 4;
  float4 s = *(const float4*)(part + idx);
  #pragma unroll
  for (int p = 1; p < KSPL; p++) {
    float4 v = *(const float4*)(part + (size_t)p * (BATCH * NHID) + idx);
    s.x += v.x; s.y += v.y; s.z += v.z; s.w += v.w;
  }
  float4 bv = *(const float4*)(bias + (idx & (NHID - 1)));
  s.x = fmaxf(s.x + bv.x, 0.0f); s.y = fmaxf(s.y + bv.y, 0.0f);
  s.z = fmaxf(s.z + bv.z, 0.0f); s.w = fmaxf(s.w + bv.w, 0.0f);
  ushort4 o;
  o.x = f2bf(s.x); o.y = f2bf(s.y); o.z = f2bf(s.z); o.w = f2bf(s.w);
  *(ushort4*)(outb + idx) = o;
}

// ---------------------------------------------------------------------------
// K5: FUSED sum-8-partials + b2 + relu (LDS tile) + w3 projection partials.
// Replaces k_finalize<8,fp32> + old k_gemm3p; removes h2 round-trip.
// Summation order over p identical to the old finalize (p ascending).
// ---------------------------------------------------------------------------
__global__ void k_gemm3p(const float* __restrict__ part,
                         const float* __restrict__ b2,
                         const float* __restrict__ w3,
                         float* __restrict__ part3) {
  int kc = blockIdx.x;             // 128 chunks of 32 k
  int t = threadIdx.x;             // 128 threads
  __shared__ float wl[32 * FGC];
  __shared__ float ht[128 * 33];   // h2 tile [m][k], +1 pad vs 32 banks
  for (int i = t; i < 32 * FGC; i += 128) wl[i] = w3[kc * 32 * FGC + i];
  int klane = t & 31, mg = t >> 5;
  float bv = b2[kc * 32 + klane];
  for (int i = 0; i < 32; i++) {
    int m = mg * 32 + i;
    const float* pp = part + (size_t)m * NHID + kc * 32 + klane;
    float s = pp[0];
    #pragma unroll
    for (int p = 1; p < 8; p++) s += pp[(size_t)p * (BATCH * NHID)];
    ht[m * 33 + klane] = fmaxf(s + bv, 0.0f);
  }
  __syncthreads();
  float acc[FGC];
  #pragma unroll
  for (int j = 0; j < FGC; j++) acc[j] = 0.0f;
  const float* hp = &ht[t * 33];
  for (int k = 0; k < 32; k++) {
    float hv = hp[k];
    const float* wp = &wl[k * FGC];
    #pragma unroll
    for (int j = 0; j < FGC; j++) acc[j] += hv * wp[j];
  }
  float* dst = part3 + (size_t)kc * (BATCH * FGC) + t * FGC;
  #pragma unroll
  for (int j = 0; j < FGC; j++) dst[j] = acc[j];
}

__global__ void k_fin3(const float* __restrict__ part3,
                       const float* __restrict__ b3,
                       float* __restrict__ out) {
  int j = blockIdx.x * 256 + threadIdx.x;
  if (j >= BATCH * FGC) return;
  float s = 0.0f;
  for (int p = 0; p < 128; p++) s += part3[(size_t)p * (BATCH * FGC) + j];
  out[j] = s + b3[j % FGC];
}

// ---------------------------------------------------------------------------
extern "C" void kernel_launch(void* const* d_in, const int* in_sizes, int n_in,
                              void* d_out, int out_size, void* d_ws, size_t ws_size,
                              hipStream_t stream) {
  const float* loc      = (const float*)d_in[0];
  const float* conf     = (const float*)d_in[1];
  const float* priors   = (const float*)d_in[2];
  const float* features = (const float*)d_in[3];
  const float* w1 = (const float*)d_in[4];
  const float* b1 = (const float*)d_in[5];
  const float* w2 = (const float*)d_in[6];
  const float* b2 = (const float*)d_in[7];
  const float* w3 = (const float*)d_in[8];
  const float* b3 = (const float*)d_in[9];
  float* out = (float*)d_out;      // [128*19 fg][128*4 boxes][128 valid]

  char* ws = (char*)d_ws;
  float* part  = (float*)ws;                                          // 16 MB
  float* part3 = (float*)(ws + (size_t)16 * 1024 * 1024);             // 1.25 MB
  u16*   featb = (u16*)(ws + (size_t)20 * 1024 * 1024);               // 128 KB
  u16*   h1b   = (u16*)(ws + (size_t)20 * 1024 * 1024 + 256 * 1024);  // 1 MB
  int4*  crop  = (int4*)(ws + (size_t)21 * 1024 * 1024 + 512 * 1024); // 2 KB
  int*   vfl   = (int*)(crop + BATCH);

  k_best<<<BATCH, 256, 0, stream>>>(conf, loc, priors,
                                    out + BATCH * FGC,
                                    out + BATCH * FGC + BATCH * 4, crop, vfl);
  k_extract<<<BATCH * (CCH / 4), 256, 0, stream>>>(features, crop, vfl, featb);
  k_mfma<4><<<dim3(64, 4), 256, 0, stream>>>(featb, w1, part, CCH);
  k_finalize_bf16<4><<<512, 256, 0, stream>>>(part, b1, h1b);
  k_mfma<8><<<dim3(64, 8), 256, 0, stream>>>(h1b, w2, part, NHID);
  k_gemm3p<<<128, 128, 0, stream>>>(part, b2, w3, part3);
  k_fin3<<<10, 256, 0, stream>>>(part3, b3, out);
}